// Round 8
// baseline (70108.490 us; speedup 1.0000x reference)
//
#include <hip/hip_runtime.h>

// Persistent layer-pipelined GRU, f32. 256 blocks x 1024 threads (16 waves/CU,
// 50% occupancy — r7's 8-wave/CU version was latency-bound at VALUBusy 36%).
// No LDS weight cache: Wh/Wx/Wout stream from L2/L3 as wave-broadcast float4
// (bandwidth trivial; LDS cache only cost occupancy). Diagonal wavefront:
// macro-step m runs A(l0,m), A(l1,m-1), A(l2,m-2) fused in one phase, then
// fused C for all three layers. 2 grid barriers per macro-step.
// Cross-block state via agent-scope relaxed atomics (MALL-coherent, no fences).

struct GruParams {
  const float* x;            // (32, 512, 128)
  const float* Wx[3][3];     // [layer][gate z,r,g]
  const float* Wh[3][3];
  const float* bias[3][3];
  const float* Wout;         // (128, 1024)
  const float* bout;         // (128)
  float* hT;                 // [3][1024][32]  (k-major, b-minor)
  float* rhT;                // [3][1024][32]
  unsigned* bar;
  float* out;                // (B,S,O)
  float* outHid;             // (B,L,H)
};

#define NW 16                       // waves per block
#define SCR (NW * 384 + 384)        // 6528 floats = 26,112 B LDS

__device__ __forceinline__ float loadc(const float* p) {
  return __hip_atomic_load((float*)p, __ATOMIC_RELAXED, __HIP_MEMORY_SCOPE_AGENT);
}
__device__ __forceinline__ void storec(float* p, float v) {
  __hip_atomic_store(p, v, __ATOMIC_RELAXED, __HIP_MEMORY_SCOPE_AGENT);
}
__device__ __forceinline__ void fma4(float& acc, float o0, float o1, float o2,
                                     float o3, const float4 v) {
  acc += o0 * v.x; acc += o1 * v.y; acc += o2 * v.z; acc += o3 * v.w;
}

// Two-level barrier: 16 groups x 16 blocks, 128B-strided lines (r6/r7-proven).
__device__ __forceinline__ void gridbar(unsigned* bar, unsigned phase, int bid) {
  __syncthreads();
  if (threadIdx.x == 0) {
    const int g = bid & 15;
    unsigned* grp   = bar + (g << 5);
    unsigned* root  = bar + 512;
    unsigned* go    = bar + 544;
    unsigned* grpGo = bar + 576 + (g << 5);
    const unsigned tgt = phase << 4;
    unsigned old = __hip_atomic_fetch_add(grp, 1u, __ATOMIC_RELAXED, __HIP_MEMORY_SCOPE_AGENT);
    if (old == tgt - 1u) {
      unsigned r = __hip_atomic_fetch_add(root, 1u, __ATOMIC_RELAXED, __HIP_MEMORY_SCOPE_AGENT);
      if (r == tgt - 1u)
        __hip_atomic_store(go, phase, __ATOMIC_RELAXED, __HIP_MEMORY_SCOPE_AGENT);
      while (__hip_atomic_load(go, __ATOMIC_RELAXED, __HIP_MEMORY_SCOPE_AGENT) < phase)
        __builtin_amdgcn_s_sleep(2);
      __hip_atomic_store(grpGo, phase, __ATOMIC_RELAXED, __HIP_MEMORY_SCOPE_AGENT);
    } else {
      while (__hip_atomic_load(grpGo, __ATOMIC_RELAXED, __HIP_MEMORY_SCOPE_AGENT) < phase)
        __builtin_amdgcn_s_sleep(2);
    }
  }
  __syncthreads();
}

// A-stage epilogue: reduce az/ar/ag over 16 waves, bias/sigmoid, emit rh.
__device__ __forceinline__ void reduceA(
    float* scratch, float (&az)[4], float (&ar)[4], float (&ag)[4],
    const float* bz, const float* br, const float* bg,
    const float* hTl, float* rhTl,
    int tid, int w, int b, int ks, int jbase,
    float& o_z, float& o_gx)
{
  #pragma unroll
  for (int jj = 0; jj < 4; ++jj) {
    az[jj] += __shfl_xor(az[jj], 32);
    ar[jj] += __shfl_xor(ar[jj], 32);
    ag[jj] += __shfl_xor(ag[jj], 32);
  }
  if (ks == 0) {
    #pragma unroll
    for (int jj = 0; jj < 4; ++jj) {
      scratch[w * 384 + (jj * 3 + 0) * 32 + b] = az[jj];
      scratch[w * 384 + (jj * 3 + 1) * 32 + b] = ar[jj];
      scratch[w * 384 + (jj * 3 + 2) * 32 + b] = ag[jj];
    }
  }
  __syncthreads();
  if (tid < 384) {
    float s = 0.f;
    #pragma unroll
    for (int ww = 0; ww < NW; ++ww) s += scratch[ww * 384 + tid];
    scratch[NW * 384 + tid] = s;
  }
  __syncthreads();
  if (tid < 128) {
    const int jj = tid >> 5, bb = tid & 31;
    const int j = jbase + jj;
    const float zp = scratch[NW * 384 + (jj * 3 + 0) * 32 + bb] + bz[j];
    const float rp = scratch[NW * 384 + (jj * 3 + 1) * 32 + bb] + br[j];
    const float gp = scratch[NW * 384 + (jj * 3 + 2) * 32 + bb] + bg[j];
    const float z = 1.f / (1.f + expf(-zp));
    const float r = 1.f / (1.f + expf(-rp));
    o_z  = z;
    o_gx = gp;
    storec(rhTl + (j << 5) + bb, r * loadc(hTl + (j << 5) + bb));
  }
  __syncthreads();
}

__global__ __launch_bounds__(1024) void gruPersist(GruParams p) {
  const int tid  = threadIdx.x;
  const int bid  = blockIdx.x;
  const int w    = tid >> 6;        // wave 0..15
  const int lane = tid & 63;
  const int b    = lane & 31;
  const int ks   = lane >> 5;
  const int jbase = bid << 2;
  __shared__ float scratch[SCR];

  float* hT0 = p.hT;  float* hT1 = p.hT + 32768;  float* hT2 = p.hT + 65536;
  float* rh0 = p.rhT; float* rh1 = p.rhT + 32768; float* rh2 = p.rhT + 65536;

  unsigned phase = 0;
  float my_z[3] = {0.f,0.f,0.f}, my_gx[3] = {0.f,0.f,0.f};

  for (int m = 0; m < 514; ++m) {
    const bool act0 = (m < 512);
    const bool act1 = (m >= 1 && m <= 512);
    const bool act2 = (m >= 2 && m <= 513);
    const int t0 = m, t1 = m - 1, t2 = m - 2, th = m - 3;

    // ========== phase 1: A(l0,t0) + A(l1,t1) + A(l2,t2) + head(th) ==========
    float a0z[4] = {0,0,0,0}, a0r[4] = {0,0,0,0}, a0g[4] = {0,0,0,0};
    if (act0) {   // l0 x-side (K=128): wave w owns k in [8w, 8w+8)
      const float* xb = p.x + ((size_t)b << 16) + ((size_t)t0 << 7);
      const int k = (w << 3) + (ks << 2);
      const float o0 = xb[k], o1 = xb[k+1], o2 = xb[k+2], o3 = xb[k+3];
      #pragma unroll
      for (int jj = 0; jj < 4; ++jj) {
        const size_t row = (size_t)(jbase + jj) * 128 + k;
        fma4(a0z[jj], o0,o1,o2,o3, *(const float4*)(p.Wx[0][0] + row));
        fma4(a0r[jj], o0,o1,o2,o3, *(const float4*)(p.Wx[0][1] + row));
        fma4(a0g[jj], o0,o1,o2,o3, *(const float4*)(p.Wx[0][2] + row));
      }
    }
    // sweep1: h0 -> l0 z/r (Wh0) + l1 z/r/g (Wx1); wave w: k in [64w, 64w+64)
    float a1z[4] = {0,0,0,0}, a1r[4] = {0,0,0,0}, a1g[4] = {0,0,0,0};
    #pragma unroll 2
    for (int i = 0; i < 8; ++i) {
      const int k = (w << 6) + (i << 3) + (ks << 2);
      const float o0 = loadc(hT0 + (k+0)*32 + b);
      const float o1 = loadc(hT0 + (k+1)*32 + b);
      const float o2 = loadc(hT0 + (k+2)*32 + b);
      const float o3 = loadc(hT0 + (k+3)*32 + b);
      #pragma unroll
      for (int jj = 0; jj < 4; ++jj) {
        const size_t row = ((size_t)(jbase + jj) << 10) + k;
        fma4(a0z[jj], o0,o1,o2,o3, *(const float4*)(p.Wh[0][0] + row));
        fma4(a0r[jj], o0,o1,o2,o3, *(const float4*)(p.Wh[0][1] + row));
        fma4(a1z[jj], o0,o1,o2,o3, *(const float4*)(p.Wx[1][0] + row));
        fma4(a1r[jj], o0,o1,o2,o3, *(const float4*)(p.Wx[1][1] + row));
        fma4(a1g[jj], o0,o1,o2,o3, *(const float4*)(p.Wx[1][2] + row));
      }
    }
    reduceA(scratch, a0z, a0r, a0g, p.bias[0][0], p.bias[0][1], p.bias[0][2],
            hT0, rh0, tid, w, b, ks, jbase, my_z[0], my_gx[0]);

    // sweep2: h1 -> l1 z/r (Wh1) + l2 z/r/g (Wx2)
    float a2z[4] = {0,0,0,0}, a2r[4] = {0,0,0,0}, a2g[4] = {0,0,0,0};
    #pragma unroll 2
    for (int i = 0; i < 8; ++i) {
      const int k = (w << 6) + (i << 3) + (ks << 2);
      const float o0 = loadc(hT1 + (k+0)*32 + b);
      const float o1 = loadc(hT1 + (k+1)*32 + b);
      const float o2 = loadc(hT1 + (k+2)*32 + b);
      const float o3 = loadc(hT1 + (k+3)*32 + b);
      #pragma unroll
      for (int jj = 0; jj < 4; ++jj) {
        const size_t row = ((size_t)(jbase + jj) << 10) + k;
        fma4(a1z[jj], o0,o1,o2,o3, *(const float4*)(p.Wh[1][0] + row));
        fma4(a1r[jj], o0,o1,o2,o3, *(const float4*)(p.Wh[1][1] + row));
        fma4(a2z[jj], o0,o1,o2,o3, *(const float4*)(p.Wx[2][0] + row));
        fma4(a2r[jj], o0,o1,o2,o3, *(const float4*)(p.Wx[2][1] + row));
        fma4(a2g[jj], o0,o1,o2,o3, *(const float4*)(p.Wx[2][2] + row));
      }
    }
    reduceA(scratch, a1z, a1r, a1g, p.bias[1][0], p.bias[1][1], p.bias[1][2],
            hT1, rh1, tid, w, b, ks, jbase, my_z[1], my_gx[1]);

    // sweep3: h2 -> l2 z/r (Wh2) + head (bid<128: o-row = bid)
    float ah = 0.f;
    #pragma unroll 2
    for (int i = 0; i < 8; ++i) {
      const int k = (w << 6) + (i << 3) + (ks << 2);
      const float o0 = loadc(hT2 + (k+0)*32 + b);
      const float o1 = loadc(hT2 + (k+1)*32 + b);
      const float o2 = loadc(hT2 + (k+2)*32 + b);
      const float o3 = loadc(hT2 + (k+3)*32 + b);
      #pragma unroll
      for (int jj = 0; jj < 4; ++jj) {
        const size_t row = ((size_t)(jbase + jj) << 10) + k;
        fma4(a2z[jj], o0,o1,o2,o3, *(const float4*)(p.Wh[2][0] + row));
        fma4(a2r[jj], o0,o1,o2,o3, *(const float4*)(p.Wh[2][1] + row));
      }
      if (bid < 128)
        fma4(ah, o0,o1,o2,o3, *(const float4*)(p.Wout + ((size_t)bid << 10) + k));
    }
    reduceA(scratch, a2z, a2r, a2g, p.bias[2][0], p.bias[2][1], p.bias[2][2],
            hT2, rh2, tid, w, b, ks, jbase, my_z[2], my_gx[2]);

    if (m >= 3) {   // head for t=th (h2(th) finalized last macro-step)
      ah += __shfl_xor(ah, 32);
      if (bid < 128 && ks == 0) scratch[w * 32 + b] = ah;
      __syncthreads();
      if (bid < 128 && tid < 32) {
        float s = 0.f;
        #pragma unroll
        for (int ww = 0; ww < NW; ++ww) s += scratch[ww * 32 + tid];
        p.out[((size_t)tid << 16) + ((size_t)th << 7) + bid] = s + p.bout[bid];
      }
      __syncthreads();
    }

    ++phase; gridbar(p.bar, phase, bid);

    // ========== phase 2: fused C for l0,l1,l2 ==========
    float c0[4] = {0,0,0,0}, c1[4] = {0,0,0,0}, c2[4] = {0,0,0,0};
    #pragma unroll 2
    for (int i = 0; i < 8; ++i) {
      const int k = (w << 6) + (i << 3) + (ks << 2);
      float r0_[4], r1_[4], r2_[4];
      #pragma unroll
      for (int q = 0; q < 4; ++q) {
        r0_[q] = loadc(rh0 + (k+q)*32 + b);
        r1_[q] = loadc(rh1 + (k+q)*32 + b);
        r2_[q] = loadc(rh2 + (k+q)*32 + b);
      }
      #pragma unroll
      for (int jj = 0; jj < 4; ++jj) {
        const size_t row = ((size_t)(jbase + jj) << 10) + k;
        fma4(c0[jj], r0_[0],r0_[1],r0_[2],r0_[3], *(const float4*)(p.Wh[0][2] + row));
        fma4(c1[jj], r1_[0],r1_[1],r1_[2],r1_[3], *(const float4*)(p.Wh[1][2] + row));
        fma4(c2[jj], r2_[0],r2_[1],r2_[2],r2_[3], *(const float4*)(p.Wh[2][2] + row));
      }
    }
    #pragma unroll
    for (int jj = 0; jj < 4; ++jj) {
      c0[jj] += __shfl_xor(c0[jj], 32);
      c1[jj] += __shfl_xor(c1[jj], 32);
      c2[jj] += __shfl_xor(c2[jj], 32);
    }
    if (ks == 0) {
      #pragma unroll
      for (int jj = 0; jj < 4; ++jj) {
        scratch[w * 384 + (0 * 4 + jj) * 32 + b] = c0[jj];
        scratch[w * 384 + (1 * 4 + jj) * 32 + b] = c1[jj];
        scratch[w * 384 + (2 * 4 + jj) * 32 + b] = c2[jj];
      }
    }
    __syncthreads();
    if (tid < 384) {
      float s = 0.f;
      #pragma unroll
      for (int ww = 0; ww < NW; ++ww) s += scratch[ww * 384 + tid];
      scratch[NW * 384 + tid] = s;
    }
    __syncthreads();
    if (tid < 128) {
      const int jj = tid >> 5, bb = tid & 31;
      const int j = jbase + jj;
      if (act0) {
        const float g = tanhf(scratch[NW * 384 + (0*4 + jj)*32 + bb] + my_gx[0]);
        const float hp = loadc(hT0 + (j << 5) + bb);
        const float hn = my_z[0] * hp + (1.f - my_z[0]) * g;
        storec(hT0 + (j << 5) + bb, hn);
        if (t0 == 511) p.outHid[bb * 3072 + j] = hn;
      }
      if (act1) {
        const float g = tanhf(scratch[NW * 384 + (1*4 + jj)*32 + bb] + my_gx[1]);
        const float hp = loadc(hT1 + (j << 5) + bb);
        const float hn = my_z[1] * hp + (1.f - my_z[1]) * g;
        storec(hT1 + (j << 5) + bb, hn);
        if (t1 == 511) p.outHid[bb * 3072 + 1024 + j] = hn;
      }
      if (act2) {
        const float g = tanhf(scratch[NW * 384 + (2*4 + jj)*32 + bb] + my_gx[2]);
        const float hp = loadc(hT2 + (j << 5) + bb);
        const float hn = my_z[2] * hp + (1.f - my_z[2]) * g;
        storec(hT2 + (j << 5) + bb, hn);
        if (t2 == 511) p.outHid[bb * 3072 + 2048 + j] = hn;
      }
    }
    __syncthreads();
    ++phase; gridbar(p.bar, phase, bid);
  } // m

  // final head: t=511
  {
    float ah = 0.f;
    if (bid < 128) {
      #pragma unroll 2
      for (int i = 0; i < 8; ++i) {
        const int k = (w << 6) + (i << 3) + (ks << 2);
        const float o0 = loadc(hT2 + (k+0)*32 + b);
        const float o1 = loadc(hT2 + (k+1)*32 + b);
        const float o2 = loadc(hT2 + (k+2)*32 + b);
        const float o3 = loadc(hT2 + (k+3)*32 + b);
        fma4(ah, o0,o1,o2,o3, *(const float4*)(p.Wout + ((size_t)bid << 10) + k));
      }
      ah += __shfl_xor(ah, 32);
      if (ks == 0) scratch[w * 32 + b] = ah;
    }
    __syncthreads();
    if (bid < 128 && tid < 32) {
      float s = 0.f;
      #pragma unroll
      for (int ww = 0; ww < NW; ++ww) s += scratch[ww * 32 + tid];
      p.out[((size_t)tid << 16) + ((size_t)511 << 7) + bid] = s + p.bout[bid];
    }
  }
}

// Zero hT, rhT, barrier region (ws poisoned 0xAA before every launch).
__global__ void initWs(float* ws, unsigned* bar) {
  const int i = blockIdx.x * 1024 + threadIdx.x;
  if (i < 196608) ws[i] = 0.f;
  if (i < 2048) bar[i] = 0u;
}

extern "C" void kernel_launch(void* const* d_in, const int* in_sizes, int n_in,
                              void* d_out, int out_size, void* d_ws, size_t ws_size,
                              hipStream_t stream)
{
  GruParams P;
  P.x = (const float*)d_in[0];
  P.Wx[0][0] = (const float*)d_in[1];  P.Wh[0][0] = (const float*)d_in[2];
  P.bias[0][0] = (const float*)d_in[3];
  P.Wx[0][1] = (const float*)d_in[4];  P.Wh[0][1] = (const float*)d_in[5];
  P.bias[0][1] = (const float*)d_in[6];
  P.Wx[0][2] = (const float*)d_in[7];  P.Wh[0][2] = (const float*)d_in[8];
  P.bias[0][2] = (const float*)d_in[9];
  for (int l = 1; l < 3; ++l) {
    const size_t off = (size_t)(l - 1) * 1048576;
    const size_t ob  = (size_t)(l - 1) * 1024;
    P.Wx[l][0] = (const float*)d_in[10] + off; P.Wh[l][0] = (const float*)d_in[11] + off;
    P.bias[l][0] = (const float*)d_in[12] + ob;
    P.Wx[l][1] = (const float*)d_in[13] + off; P.Wh[l][1] = (const float*)d_in[14] + off;
    P.bias[l][1] = (const float*)d_in[15] + ob;
    P.Wx[l][2] = (const float*)d_in[16] + off; P.Wh[l][2] = (const float*)d_in[17] + off;
    P.bias[l][2] = (const float*)d_in[18] + ob;
  }
  P.Wout = (const float*)d_in[19];
  P.bout = (const float*)d_in[20];

  float* ws = (float*)d_ws;
  P.hT  = ws;                          // 3*32768
  P.rhT = ws + 98304;                  // 3*32768
  P.bar = (unsigned*)(ws + 196608);    // 2048 uints
  P.out = (float*)d_out;
  P.outHid = P.out + 2097152;

  initWs<<<192, 1024, 0, stream>>>(ws, P.bar);
  gruPersist<<<256, 1024, 0, stream>>>(P);
}

// Round 10
// 44388.806 us; speedup vs baseline: 1.5794x; 1.5794x over previous
//
#include <hip/hip_runtime.h>

// Persistent layer-pipelined GRU, f32. 256 blocks x 512 threads, 1 block/CU.
// Base = r7 skeleton (post-timing-stable). Changes vs r7:
//  (1) phase-1 sweeps fused with NO intra-phase __syncthreads until one
//      combined reduction (14 -> 4 full vmcnt drains per macro-step);
//  (2) activations in float2 chunks [k/2][b][2], read via 64-bit relaxed
//      agent-scope atomic loads (global_load_dwordx2 sc1) — half the loads;
//  (3) LDS caches Whz/Whr only (98 KB); Whg streams from L2 in phase 2.
// Cross-block state via agent-scope relaxed atomics (MALL-coherent, no
// fences); two-level grid barrier (r6-proven).

struct GruParams {
  const float* x;            // (32, 512, 128)
  const float* Wx[3][3];     // [layer][gate z,r,g]
  const float* Wh[3][3];
  const float* bias[3][3];
  const float* Wout;         // (128, 1024)
  const float* bout;         // (128)
  float* hT;                 // [3][512 kp][32 b][2]  float2-chunked
  float* rhT;                // same layout
  unsigned* bar;
  float* out;                // (B,S,O)
  float* outHid;             // (B,L,H)
};

#define WCACHE 24576               // 6 slices (Whz,Whr x 3 layers) * 4096 fl
#define PWAVE 1184                 // per-wave scratch: 9 sets*4jj*32 + 32 head
#define LDSF (WCACHE + 8 * PWAVE + PWAVE)   // 35232 floats = 140,928 B
#define LDSB (LDSF * 4)

extern __shared__ float lds[];

__device__ __forceinline__ float loadc(const float* p) {
  return __hip_atomic_load((float*)p, __ATOMIC_RELAXED, __HIP_MEMORY_SCOPE_AGENT);
}
__device__ __forceinline__ void storec(float* p, float v) {
  __hip_atomic_store(p, v, __ATOMIC_RELAXED, __HIP_MEMORY_SCOPE_AGENT);
}
__device__ __forceinline__ float2 loadc2(const float* p) {
  unsigned long long v = __hip_atomic_load((const unsigned long long*)p,
                                           __ATOMIC_RELAXED, __HIP_MEMORY_SCOPE_AGENT);
  union { unsigned long long u; float2 f; } c; c.u = v; return c.f;
}
__device__ __forceinline__ void fma4(float& acc, float o0, float o1, float o2,
                                     float o3, const float4 v) {
  acc += o0 * v.x; acc += o1 * v.y; acc += o2 * v.z; acc += o3 * v.w;
}

// Two-level barrier: 16 groups x 16 blocks, 128B-strided lines (r6/r7-proven).
__device__ __forceinline__ void gridbar(unsigned* bar, unsigned phase, int bid) {
  __syncthreads();
  if (threadIdx.x == 0) {
    const int g = bid & 15;
    unsigned* grp   = bar + (g << 5);
    unsigned* root  = bar + 512;
    unsigned* go    = bar + 544;
    unsigned* grpGo = bar + 576 + (g << 5);
    const unsigned tgt = phase << 4;
    unsigned old = __hip_atomic_fetch_add(grp, 1u, __ATOMIC_RELAXED, __HIP_MEMORY_SCOPE_AGENT);
    if (old == tgt - 1u) {
      unsigned r = __hip_atomic_fetch_add(root, 1u, __ATOMIC_RELAXED, __HIP_MEMORY_SCOPE_AGENT);
      if (r == tgt - 1u)
        __hip_atomic_store(go, phase, __ATOMIC_RELAXED, __HIP_MEMORY_SCOPE_AGENT);
      while (__hip_atomic_load(go, __ATOMIC_RELAXED, __HIP_MEMORY_SCOPE_AGENT) < phase)
        __builtin_amdgcn_s_sleep(2);
      __hip_atomic_store(grpGo, phase, __ATOMIC_RELAXED, __HIP_MEMORY_SCOPE_AGENT);
    } else {
      while (__hip_atomic_load(grpGo, __ATOMIC_RELAXED, __HIP_MEMORY_SCOPE_AGENT) < phase)
        __builtin_amdgcn_s_sleep(2);
    }
  }
  __syncthreads();
}

__global__ __launch_bounds__(512, 2) void gruPersist(GruParams p) {
  const int tid  = threadIdx.x;
  const int bid  = blockIdx.x;
  const int w    = tid >> 6;        // wave 0..7
  const int lane = tid & 63;
  const int b    = lane & 31;
  const int ks   = lane >> 5;
  const int jbase = bid << 2;
  float* scratch = lds + WCACHE;          // 8 * PWAVE
  float* comb    = scratch + 8 * PWAVE;   // PWAVE
  float* my      = scratch + w * PWAVE;

  // cache Whz/Whr slices (6 x 4096 fl) in LDS; slice s -> layer s/2, gate s&1
  for (int idx = tid; idx < WCACHE; idx += 512) {
    const int s = idx >> 12, rem = idx & 4095;
    lds[idx] = p.Wh[s >> 1][s & 1][((size_t)jbase << 10) + rem];
  }
  __syncthreads();

  float* hq0 = p.hT;  float* hq1 = p.hT + 32768;  float* hq2 = p.hT + 65536;
  float* rq0 = p.rhT; float* rq1 = p.rhT + 32768; float* rq2 = p.rhT + 65536;
  const float* whz0 = lds;          const float* whr0 = lds + 4096;
  const float* whz1 = lds + 8192;   const float* whr1 = lds + 12288;
  const float* whz2 = lds + 16384;  const float* whr2 = lds + 20480;

  unsigned phase = 0;
  float my_z[3] = {0.f,0.f,0.f}, my_gx[3] = {0.f,0.f,0.f};

  for (int m = 0; m < 514; ++m) {
    const bool act0 = (m < 512);
    const bool act1 = (m >= 1 && m <= 512);
    const bool act2 = (m >= 2 && m <= 513);
    const int t0 = m, t1 = m - 1, t2 = m - 2, th = m - 3;

    // ===== phase 1: all A-stage dots, fused, no intra-sweep barriers =====
    float a0z[4]={0,0,0,0}, a0r[4]={0,0,0,0}, a0g[4]={0,0,0,0};
    float a1z[4]={0,0,0,0}, a1r[4]={0,0,0,0}, a1g[4]={0,0,0,0};
    float a2z[4]={0,0,0,0}, a2r[4]={0,0,0,0}, a2g[4]={0,0,0,0};
    float ah = 0.f;

    if (act0) {   // l0 x-side (K=128): wave w covers k [16w,16w+16)
      const float* xb = p.x + ((size_t)b << 16) + ((size_t)t0 << 7);
      #pragma unroll
      for (int i = 0; i < 2; ++i) {
        const int k = (w << 4) + (i << 3) + (ks << 2);
        const float4 xv = *(const float4*)(xb + k);
        #pragma unroll
        for (int jj = 0; jj < 4; ++jj) {
          const size_t row = (size_t)(jbase + jj) * 128 + k;
          fma4(a0z[jj], xv.x,xv.y,xv.z,xv.w, *(const float4*)(p.Wx[0][0] + row));
          fma4(a0r[jj], xv.x,xv.y,xv.z,xv.w, *(const float4*)(p.Wx[0][1] + row));
          fma4(a0g[jj], xv.x,xv.y,xv.z,xv.w, *(const float4*)(p.Wx[0][2] + row));
        }
      }
    }

    // loop1: h0 -> l0 z/r (LDS) + l1 z/r/g (Wx1, L2)
    #pragma unroll 2
    for (int i = 0; i < 16; ++i) {
      const int kp = (w << 6) + (i << 2) + (ks << 1);
      const int k4 = kp << 1;
      const float2 q0 = loadc2(hq0 + kp * 64 + b * 2);
      const float2 q1 = loadc2(hq0 + (kp + 1) * 64 + b * 2);
      #pragma unroll
      for (int jj = 0; jj < 4; ++jj) {
        const size_t row = ((size_t)(jbase + jj) << 10) + k4;
        fma4(a0z[jj], q0.x,q0.y,q1.x,q1.y, *(const float4*)(whz0 + (jj<<10) + k4));
        fma4(a0r[jj], q0.x,q0.y,q1.x,q1.y, *(const float4*)(whr0 + (jj<<10) + k4));
        fma4(a1z[jj], q0.x,q0.y,q1.x,q1.y, *(const float4*)(p.Wx[1][0] + row));
        fma4(a1r[jj], q0.x,q0.y,q1.x,q1.y, *(const float4*)(p.Wx[1][1] + row));
        fma4(a1g[jj], q0.x,q0.y,q1.x,q1.y, *(const float4*)(p.Wx[1][2] + row));
      }
    }
    #pragma unroll
    for (int jj = 0; jj < 4; ++jj) {
      a0z[jj] += __shfl_xor(a0z[jj], 32);
      a0r[jj] += __shfl_xor(a0r[jj], 32);
      a0g[jj] += __shfl_xor(a0g[jj], 32);
      a1g[jj] += __shfl_xor(a1g[jj], 32);
    }
    if (ks == 0) {
      #pragma unroll
      for (int jj = 0; jj < 4; ++jj) {
        my[(0*4+jj)*32 + b] = a0z[jj];   // set 0: l0 z
        my[(1*4+jj)*32 + b] = a0r[jj];   // set 1: l0 r
        my[(2*4+jj)*32 + b] = a0g[jj];   // set 2: l0 g
        my[(5*4+jj)*32 + b] = a1g[jj];   // set 5: l1 g
      }
    }

    // loop2: h1 -> l1 z/r (LDS) + l2 z/r/g (Wx2, L2)
    #pragma unroll 2
    for (int i = 0; i < 16; ++i) {
      const int kp = (w << 6) + (i << 2) + (ks << 1);
      const int k4 = kp << 1;
      const float2 q0 = loadc2(hq1 + kp * 64 + b * 2);
      const float2 q1 = loadc2(hq1 + (kp + 1) * 64 + b * 2);
      #pragma unroll
      for (int jj = 0; jj < 4; ++jj) {
        const size_t row = ((size_t)(jbase + jj) << 10) + k4;
        fma4(a1z[jj], q0.x,q0.y,q1.x,q1.y, *(const float4*)(whz1 + (jj<<10) + k4));
        fma4(a1r[jj], q0.x,q0.y,q1.x,q1.y, *(const float4*)(whr1 + (jj<<10) + k4));
        fma4(a2z[jj], q0.x,q0.y,q1.x,q1.y, *(const float4*)(p.Wx[2][0] + row));
        fma4(a2r[jj], q0.x,q0.y,q1.x,q1.y, *(const float4*)(p.Wx[2][1] + row));
        fma4(a2g[jj], q0.x,q0.y,q1.x,q1.y, *(const float4*)(p.Wx[2][2] + row));
      }
    }
    #pragma unroll
    for (int jj = 0; jj < 4; ++jj) {
      a1z[jj] += __shfl_xor(a1z[jj], 32);
      a1r[jj] += __shfl_xor(a1r[jj], 32);
      a2g[jj] += __shfl_xor(a2g[jj], 32);
    }
    if (ks == 0) {
      #pragma unroll
      for (int jj = 0; jj < 4; ++jj) {
        my[(3*4+jj)*32 + b] = a1z[jj];   // set 3: l1 z
        my[(4*4+jj)*32 + b] = a1r[jj];   // set 4: l1 r
        my[(8*4+jj)*32 + b] = a2g[jj];   // set 8: l2 g
      }
    }

    // loop3: h2 -> l2 z/r (LDS) + head (bid<128: Wout row bid)
    #pragma unroll 2
    for (int i = 0; i < 16; ++i) {
      const int kp = (w << 6) + (i << 2) + (ks << 1);
      const int k4 = kp << 1;
      const float2 q0 = loadc2(hq2 + kp * 64 + b * 2);
      const float2 q1 = loadc2(hq2 + (kp + 1) * 64 + b * 2);
      #pragma unroll
      for (int jj = 0; jj < 4; ++jj) {
        fma4(a2z[jj], q0.x,q0.y,q1.x,q1.y, *(const float4*)(whz2 + (jj<<10) + k4));
        fma4(a2r[jj], q0.x,q0.y,q1.x,q1.y, *(const float4*)(whr2 + (jj<<10) + k4));
      }
      if (bid < 128)
        fma4(ah, q0.x,q0.y,q1.x,q1.y, *(const float4*)(p.Wout + ((size_t)bid << 10) + k4));
    }
    #pragma unroll
    for (int jj = 0; jj < 4; ++jj) {
      a2z[jj] += __shfl_xor(a2z[jj], 32);
      a2r[jj] += __shfl_xor(a2r[jj], 32);
    }
    ah += __shfl_xor(ah, 32);
    if (ks == 0) {
      #pragma unroll
      for (int jj = 0; jj < 4; ++jj) {
        my[(6*4+jj)*32 + b] = a2z[jj];   // set 6: l2 z
        my[(7*4+jj)*32 + b] = a2r[jj];   // set 7: l2 r
      }
      my[1152 + b] = ah;
    }

    // single combined reduction (2 syncthreads total for all of phase 1)
    __syncthreads();
    for (int s = tid; s < PWAVE; s += 512) {
      float v = 0.f;
      #pragma unroll
      for (int ww = 0; ww < 8; ++ww) v += scratch[ww * PWAVE + s];
      comb[s] = v;
    }
    __syncthreads();
    if (tid < 128) {
      const int jj = tid >> 5, bb = tid & 31;
      const int j = jbase + jj;
      const int off = (j >> 1) * 64 + bb * 2 + (j & 1);
      #pragma unroll
      for (int l = 0; l < 3; ++l) {
        const float zp = comb[((l*3+0)*4 + jj)*32 + bb] + p.bias[l][0][j];
        const float rp = comb[((l*3+1)*4 + jj)*32 + bb] + p.bias[l][1][j];
        const float gp = comb[((l*3+2)*4 + jj)*32 + bb] + p.bias[l][2][j];
        const float z = 1.f / (1.f + expf(-zp));
        const float r = 1.f / (1.f + expf(-rp));
        my_z[l]  = z;
        my_gx[l] = gp;
        float* hq = (l == 0) ? hq0 : (l == 1) ? hq1 : hq2;
        float* rq = (l == 0) ? rq0 : (l == 1) ? rq1 : rq2;
        storec(rq + off, r * loadc(hq + off));
      }
    }
    if (m >= 3 && bid < 128 && tid < 32)
      p.out[((size_t)tid << 16) + ((size_t)th << 7) + bid] = comb[1152 + tid] + p.bout[bid];

    ++phase; gridbar(p.bar, phase, bid);

    // ===== phase 2: fused C for l0,l1,l2 (Whg from L2) =====
    float c0[4]={0,0,0,0}, c1[4]={0,0,0,0}, c2[4]={0,0,0,0};
    #pragma unroll 2
    for (int i = 0; i < 16; ++i) {
      const int kp = (w << 6) + (i << 2) + (ks << 1);
      const int k4 = kp << 1;
      const float2 r00 = loadc2(rq0 + kp * 64 + b * 2);
      const float2 r01 = loadc2(rq0 + (kp + 1) * 64 + b * 2);
      const float2 r10 = loadc2(rq1 + kp * 64 + b * 2);
      const float2 r11 = loadc2(rq1 + (kp + 1) * 64 + b * 2);
      const float2 r20 = loadc2(rq2 + kp * 64 + b * 2);
      const float2 r21 = loadc2(rq2 + (kp + 1) * 64 + b * 2);
      #pragma unroll
      for (int jj = 0; jj < 4; ++jj) {
        const size_t row = ((size_t)(jbase + jj) << 10) + k4;
        fma4(c0[jj], r00.x,r00.y,r01.x,r01.y, *(const float4*)(p.Wh[0][2] + row));
        fma4(c1[jj], r10.x,r10.y,r11.x,r11.y, *(const float4*)(p.Wh[1][2] + row));
        fma4(c2[jj], r20.x,r20.y,r21.x,r21.y, *(const float4*)(p.Wh[2][2] + row));
      }
    }
    #pragma unroll
    for (int jj = 0; jj < 4; ++jj) {
      c0[jj] += __shfl_xor(c0[jj], 32);
      c1[jj] += __shfl_xor(c1[jj], 32);
      c2[jj] += __shfl_xor(c2[jj], 32);
    }
    if (ks == 0) {
      #pragma unroll
      for (int jj = 0; jj < 4; ++jj) {
        my[(0*4+jj)*32 + b] = c0[jj];
        my[(1*4+jj)*32 + b] = c1[jj];
        my[(2*4+jj)*32 + b] = c2[jj];
      }
    }
    __syncthreads();
    if (tid < 384) {
      float v = 0.f;
      #pragma unroll
      for (int ww = 0; ww < 8; ++ww) v += scratch[ww * PWAVE + tid];
      comb[tid] = v;
    }
    __syncthreads();
    if (tid < 128) {
      const int jj = tid >> 5, bb = tid & 31;
      const int j = jbase + jj;
      const int off = (j >> 1) * 64 + bb * 2 + (j & 1);
      if (act0) {
        const float g = tanhf(comb[(0*4+jj)*32 + bb] + my_gx[0]);
        const float hn = my_z[0] * loadc(hq0 + off) + (1.f - my_z[0]) * g;
        storec(hq0 + off, hn);
        if (t0 == 511) p.outHid[bb * 3072 + j] = hn;
      }
      if (act1) {
        const float g = tanhf(comb[(1*4+jj)*32 + bb] + my_gx[1]);
        const float hn = my_z[1] * loadc(hq1 + off) + (1.f - my_z[1]) * g;
        storec(hq1 + off, hn);
        if (t1 == 511) p.outHid[bb * 3072 + 1024 + j] = hn;
      }
      if (act2) {
        const float g = tanhf(comb[(2*4+jj)*32 + bb] + my_gx[2]);
        const float hn = my_z[2] * loadc(hq2 + off) + (1.f - my_z[2]) * g;
        storec(hq2 + off, hn);
        if (t2 == 511) p.outHid[bb * 3072 + 2048 + j] = hn;
      }
    }
    ++phase; gridbar(p.bar, phase, bid);
  } // m

  // final head: t=511 (h2(511) finalized in last C phase)
  {
    float ah = 0.f;
    if (bid < 128) {
      #pragma unroll 2
      for (int i = 0; i < 16; ++i) {
        const int kp = (w << 6) + (i << 2) + (ks << 1);
        const int k4 = kp << 1;
        const float2 q0 = loadc2(hq2 + kp * 64 + b * 2);
        const float2 q1 = loadc2(hq2 + (kp + 1) * 64 + b * 2);
        fma4(ah, q0.x,q0.y,q1.x,q1.y, *(const float4*)(p.Wout + ((size_t)bid << 10) + k4));
      }
      ah += __shfl_xor(ah, 32);
      if (ks == 0) my[1152 + b] = ah;
    }
    __syncthreads();
    if (bid < 128 && tid < 32) {
      float s = 0.f;
      #pragma unroll
      for (int ww = 0; ww < 8; ++ww) s += scratch[ww * PWAVE + 1152 + tid];
      p.out[((size_t)tid << 16) + ((size_t)511 << 7) + bid] = s + p.bout[bid];
    }
  }
}

// Zero hT, rhT, barrier region (ws poisoned 0xAA before every launch).
__global__ void initWs(float* ws, unsigned* bar) {
  const int i = blockIdx.x * 1024 + threadIdx.x;
  if (i < 196608) ws[i] = 0.f;
  if (i < 2048) bar[i] = 0u;
}

extern "C" void kernel_launch(void* const* d_in, const int* in_sizes, int n_in,
                              void* d_out, int out_size, void* d_ws, size_t ws_size,
                              hipStream_t stream)
{
  GruParams P;
  P.x = (const float*)d_in[0];
  P.Wx[0][0] = (const float*)d_in[1];  P.Wh[0][0] = (const float*)d_in[2];
  P.bias[0][0] = (const float*)d_in[3];
  P.Wx[0][1] = (const float*)d_in[4];  P.Wh[0][1] = (const float*)d_in[5];
  P.bias[0][1] = (const float*)d_in[6];
  P.Wx[0][2] = (const float*)d_in[7];  P.Wh[0][2] = (const float*)d_in[8];
  P.bias[0][2] = (const float*)d_in[9];
  for (int l = 1; l < 3; ++l) {
    const size_t off = (size_t)(l - 1) * 1048576;
    const size_t ob  = (size_t)(l - 1) * 1024;
    P.Wx[l][0] = (const float*)d_in[10] + off; P.Wh[l][0] = (const float*)d_in[11] + off;
    P.bias[l][0] = (const float*)d_in[12] + ob;
    P.Wx[l][1] = (const float*)d_in[13] + off; P.Wh[l][1] = (const float*)d_in[14] + off;
    P.bias[l][1] = (const float*)d_in[15] + ob;
    P.Wx[l][2] = (const float*)d_in[16] + off; P.Wh[l][2] = (const float*)d_in[17] + off;
    P.bias[l][2] = (const float*)d_in[18] + ob;
  }
  P.Wout = (const float*)d_in[19];
  P.bout = (const float*)d_in[20];

  float* ws = (float*)d_ws;
  P.hT  = ws;                          // 3*32768
  P.rhT = ws + 98304;                  // 3*32768
  P.bar = (unsigned*)(ws + 196608);    // 2048 uints
  P.out = (float*)d_out;
  P.outHid = P.out + 2097152;

  hipFuncSetAttribute(reinterpret_cast<const void*>(gruPersist),
                      hipFuncAttributeMaxDynamicSharedMemorySize, LDSB);

  initWs<<<192, 1024, 0, stream>>>(ws, P.bar);
  gruPersist<<<256, 512, LDSB, stream>>>(P);
}

// Round 11
// 25013.446 us; speedup vs baseline: 2.8028x; 1.7746x over previous
//
#include <hip/hip_runtime.h>

// Persistent diagonal-pipelined GRU. ALL weights bf16-packed in LDS (122.9 KB:
// Wh z/r/g x3 + Wx1/Wx2 z/r/g, 4 j-rows per block) -> phases read zero weight
// bytes from L2/HBM (r6-r10 lesson: every streamed-weight variant regressed).
// f32 accumulate via v_dot2_f32_bf16 (2 MAC/instr) when available.
// Activations transported as packed bf16 via MALL-coherent relaxed atomics;
// h-state f32, owner-thread-private (recurrence chain + outHid stay f32).
// 256 blocks x 512 threads, 1 block/CU; 2 grid barriers per macro-step.

#ifndef __has_builtin
#define __has_builtin(x) 0
#endif
#if __has_builtin(__builtin_amdgcn_fdot2_f32_bf16)
#define HAS_DOT2 1
typedef __bf16 bf16x2 __attribute__((ext_vector_type(2)));
#else
#define HAS_DOT2 0
#endif

struct GruParams {
  const float* x;            // (32, 512, 128)
  const float* Wx[3][3];     // [layer][gate z,r,g]
  const float* Wh[3][3];
  const float* bias[3][3];
  const float* Wout;         // (128, 1024)
  const float* bout;         // (128)
  unsigned* hP;              // [3][512 kp][32 b] packed bf16 pairs
  unsigned* rhP;             // same layout
  float* hF;                 // [3][1024 j][32 b] f32 (owner-private)
  unsigned* bar;
  float* out;                // (B,S,O)
  float* outHid;             // (B,L,H)
};

// LDS dword map: 15 weight slices x 2048 dwords, Wout 512, scratch 9472 fl
#define WH0z 0
#define WH0r 2048
#define WH0g 4096
#define WH1z 6144
#define WH1r 8192
#define WH1g 10240
#define WH2z 12288
#define WH2r 14336
#define WH2g 16384
#define WX1z 18432
#define WX1r 20480
#define WX1g 22528
#define WX2z 24576
#define WX2r 26624
#define WX2g 28672
#define WOUTO 30720
#define SCRO  31232
#define LDSB ((SCRO + 8 * 1184) * 4)    // 162,816 B <= 160 KiB

extern __shared__ unsigned lds_u[];

__device__ __forceinline__ unsigned loadcu(const unsigned* p_) {
  return __hip_atomic_load(p_, __ATOMIC_RELAXED, __HIP_MEMORY_SCOPE_AGENT);
}
__device__ __forceinline__ void storecu(unsigned* p_, unsigned v) {
  __hip_atomic_store(p_, v, __ATOMIC_RELAXED, __HIP_MEMORY_SCOPE_AGENT);
}

__device__ __forceinline__ unsigned short f2bfu(float f) {   // RNE
  union { float f; unsigned u; } c; c.f = f;
  unsigned r = c.u + 0x7fffu + ((c.u >> 16) & 1u);
  return (unsigned short)(r >> 16);
}
__device__ __forceinline__ unsigned pack2(float f0, float f1) {
  return ((unsigned)f2bfu(f1) << 16) | (unsigned)f2bfu(f0);
}

// acc += dot(bf16x2(a), bf16x2(w)) in f32
__device__ __forceinline__ float d2(float acc, unsigned a, unsigned w) {
#if HAS_DOT2
  return __builtin_amdgcn_fdot2_f32_bf16(__builtin_bit_cast(bf16x2, a),
                                         __builtin_bit_cast(bf16x2, w),
                                         acc, false);
#else
  union { unsigned u; float f; } al, ah, wl, wh;
  al.u = a << 16; ah.u = a & 0xffff0000u;
  wl.u = w << 16; wh.u = w & 0xffff0000u;
  return acc + al.f * wl.f + ah.f * wh.f;
#endif
}
__device__ __forceinline__ void fma4(float& acc, float o0, float o1, float o2,
                                     float o3, const float4 v) {
  acc += o0 * v.x; acc += o1 * v.y; acc += o2 * v.z; acc += o3 * v.w;
}

// Two-level barrier: 16 groups x 16 blocks, 128B-strided lines (r6-proven).
__device__ __forceinline__ void gridbar(unsigned* bar, unsigned phase, int bid) {
  __syncthreads();
  if (threadIdx.x == 0) {
    const int g = bid & 15;
    unsigned* grp   = bar + (g << 5);
    unsigned* root  = bar + 512;
    unsigned* go    = bar + 544;
    unsigned* grpGo = bar + 576 + (g << 5);
    const unsigned tgt = phase << 4;
    unsigned old = __hip_atomic_fetch_add(grp, 1u, __ATOMIC_RELAXED, __HIP_MEMORY_SCOPE_AGENT);
    if (old == tgt - 1u) {
      unsigned r = __hip_atomic_fetch_add(root, 1u, __ATOMIC_RELAXED, __HIP_MEMORY_SCOPE_AGENT);
      if (r == tgt - 1u)
        __hip_atomic_store(go, phase, __ATOMIC_RELAXED, __HIP_MEMORY_SCOPE_AGENT);
      while (__hip_atomic_load(go, __ATOMIC_RELAXED, __HIP_MEMORY_SCOPE_AGENT) < phase)
        __builtin_amdgcn_s_sleep(2);
      __hip_atomic_store(grpGo, phase, __ATOMIC_RELAXED, __HIP_MEMORY_SCOPE_AGENT);
    } else {
      while (__hip_atomic_load(grpGo, __ATOMIC_RELAXED, __HIP_MEMORY_SCOPE_AGENT) < phase)
        __builtin_amdgcn_s_sleep(2);
    }
  }
  __syncthreads();
}

__global__ __launch_bounds__(512, 2) void gruPersist(GruParams p) {
  const int tid  = threadIdx.x;
  const int bid  = blockIdx.x;
  const int w    = tid >> 6;        // wave 0..7
  const int lane = tid & 63;
  const int b    = lane & 31;
  const int ks   = lane >> 5;
  const int jbase = bid << 2;
  float* scratch = (float*)(lds_u + SCRO);
  float* my      = scratch + w * 1184;

  // ---- one-time: convert this block's weight slices f32 -> packed bf16 ----
  for (int d = tid; d < 15 * 2048; d += 512) {
    const int s = d >> 11, rem = d & 2047;
    const int jj = rem >> 9, kp = rem & 511;
    const float* src;
    if (s < 9)       src = p.Wh[s / 3][s % 3];
    else if (s < 12) src = p.Wx[1][s - 9];
    else             src = p.Wx[2][s - 12];
    const size_t base = (size_t)(jbase + jj) * 1024 + (size_t)(kp << 1);
    lds_u[d] = pack2(src[base], src[base + 1]);
  }
  if (bid < 128) {   // Wout row `bid`
    const size_t base = (size_t)bid * 1024 + (size_t)(tid << 1);
    lds_u[WOUTO + tid] = pack2(p.Wout[base], p.Wout[base + 1]);
  }
  __syncthreads();

  unsigned* hP0 = p.hP;            unsigned* hP1 = p.hP + 16384;
  unsigned* hP2 = p.hP + 32768;
  unsigned* rq0 = p.rhP;           unsigned* rq1 = p.rhP + 16384;
  unsigned* rq2 = p.rhP + 32768;

  unsigned phase = 0;
  float my_z[3][2], my_gx[3][2];
  #pragma unroll
  for (int l = 0; l < 3; ++l) { my_z[l][0]=my_z[l][1]=my_gx[l][0]=my_gx[l][1]=0.f; }

  for (int m = 0; m < 514; ++m) {
    const bool act0 = (m < 512);
    const bool act1 = (m >= 1 && m <= 512);
    const bool act2 = (m >= 2 && m <= 513);
    const int t0 = m, t1 = m - 1, t2 = m - 2, th = m - 3;

    // ===================== phase 1: all A dots ============================
    float a0z[4]={0,0,0,0}, a0r[4]={0,0,0,0}, a0g[4]={0,0,0,0};
    float a1z[4]={0,0,0,0}, a1r[4]={0,0,0,0}, a1g[4]={0,0,0,0};
    float a2z[4]={0,0,0,0}, a2r[4]={0,0,0,0}, a2g[4]={0,0,0,0};
    float ah = 0.f;

    if (act0) {   // l0 x-side (K=128, f32 from L2): wave w owns k [16w,16w+16)
      const float* xb = p.x + ((size_t)b << 16) + ((size_t)t0 << 7);
      #pragma unroll
      for (int i = 0; i < 2; ++i) {
        const int k = (w << 4) + (i << 3) + (ks << 2);
        const float4 xv = *(const float4*)(xb + k);
        #pragma unroll
        for (int jj = 0; jj < 4; ++jj) {
          const size_t row = (size_t)(jbase + jj) * 128 + k;
          fma4(a0z[jj], xv.x,xv.y,xv.z,xv.w, *(const float4*)(p.Wx[0][0] + row));
          fma4(a0r[jj], xv.x,xv.y,xv.z,xv.w, *(const float4*)(p.Wx[0][1] + row));
          fma4(a0g[jj], xv.x,xv.y,xv.z,xv.w, *(const float4*)(p.Wx[0][2] + row));
        }
      }
    }

    // sweep1 over h0: l0 z/r (Wh0) + l1 z/r/g (Wx1)
    #pragma unroll 2
    for (int i = 0; i < 16; ++i) {
      const int kp0 = (w << 6) + (i << 2) + (ks << 1);
      const unsigned a0 = loadcu(hP0 + kp0 * 32 + b);
      const unsigned a1 = loadcu(hP0 + (kp0 + 1) * 32 + b);
      #pragma unroll
      for (int jj = 0; jj < 4; ++jj) {
        const int wo = (jj << 9) + kp0;
        uint2 wv;
        wv = *(const uint2*)(lds_u + WH0z + wo); a0z[jj] = d2(d2(a0z[jj], a0, wv.x), a1, wv.y);
        wv = *(const uint2*)(lds_u + WH0r + wo); a0r[jj] = d2(d2(a0r[jj], a0, wv.x), a1, wv.y);
        wv = *(const uint2*)(lds_u + WX1z + wo); a1z[jj] = d2(d2(a1z[jj], a0, wv.x), a1, wv.y);
        wv = *(const uint2*)(lds_u + WX1r + wo); a1r[jj] = d2(d2(a1r[jj], a0, wv.x), a1, wv.y);
        wv = *(const uint2*)(lds_u + WX1g + wo); a1g[jj] = d2(d2(a1g[jj], a0, wv.x), a1, wv.y);
      }
    }
    #pragma unroll
    for (int jj = 0; jj < 4; ++jj) {
      a0z[jj] += __shfl_xor(a0z[jj], 32);
      a0r[jj] += __shfl_xor(a0r[jj], 32);
      a0g[jj] += __shfl_xor(a0g[jj], 32);
      a1g[jj] += __shfl_xor(a1g[jj], 32);
    }
    if (ks == 0) {
      #pragma unroll
      for (int jj = 0; jj < 4; ++jj) {
        my[(0*4+jj)*32 + b] = a0z[jj];
        my[(1*4+jj)*32 + b] = a0r[jj];
        my[(2*4+jj)*32 + b] = a0g[jj];
        my[(5*4+jj)*32 + b] = a1g[jj];
      }
    }

    // sweep2 over h1: l1 z/r (Wh1) + l2 z/r/g (Wx2)
    #pragma unroll 2
    for (int i = 0; i < 16; ++i) {
      const int kp0 = (w << 6) + (i << 2) + (ks << 1);
      const unsigned a0 = loadcu(hP1 + kp0 * 32 + b);
      const unsigned a1 = loadcu(hP1 + (kp0 + 1) * 32 + b);
      #pragma unroll
      for (int jj = 0; jj < 4; ++jj) {
        const int wo = (jj << 9) + kp0;
        uint2 wv;
        wv = *(const uint2*)(lds_u + WH1z + wo); a1z[jj] = d2(d2(a1z[jj], a0, wv.x), a1, wv.y);
        wv = *(const uint2*)(lds_u + WH1r + wo); a1r[jj] = d2(d2(a1r[jj], a0, wv.x), a1, wv.y);
        wv = *(const uint2*)(lds_u + WX2z + wo); a2z[jj] = d2(d2(a2z[jj], a0, wv.x), a1, wv.y);
        wv = *(const uint2*)(lds_u + WX2r + wo); a2r[jj] = d2(d2(a2r[jj], a0, wv.x), a1, wv.y);
        wv = *(const uint2*)(lds_u + WX2g + wo); a2g[jj] = d2(d2(a2g[jj], a0, wv.x), a1, wv.y);
      }
    }
    #pragma unroll
    for (int jj = 0; jj < 4; ++jj) {
      a1z[jj] += __shfl_xor(a1z[jj], 32);
      a1r[jj] += __shfl_xor(a1r[jj], 32);
      a2g[jj] += __shfl_xor(a2g[jj], 32);
    }
    if (ks == 0) {
      #pragma unroll
      for (int jj = 0; jj < 4; ++jj) {
        my[(3*4+jj)*32 + b] = a1z[jj];
        my[(4*4+jj)*32 + b] = a1r[jj];
        my[(8*4+jj)*32 + b] = a2g[jj];
      }
    }

    // sweep3 over h2: l2 z/r (Wh2) + head (bid<128: Wout row bid)
    #pragma unroll 2
    for (int i = 0; i < 16; ++i) {
      const int kp0 = (w << 6) + (i << 2) + (ks << 1);
      const unsigned a0 = loadcu(hP2 + kp0 * 32 + b);
      const unsigned a1 = loadcu(hP2 + (kp0 + 1) * 32 + b);
      #pragma unroll
      for (int jj = 0; jj < 4; ++jj) {
        const int wo = (jj << 9) + kp0;
        uint2 wv;
        wv = *(const uint2*)(lds_u + WH2z + wo); a2z[jj] = d2(d2(a2z[jj], a0, wv.x), a1, wv.y);
        wv = *(const uint2*)(lds_u + WH2r + wo); a2r[jj] = d2(d2(a2r[jj], a0, wv.x), a1, wv.y);
      }
      if (bid < 128) {
        const uint2 wv = *(const uint2*)(lds_u + WOUTO + kp0);
        ah = d2(d2(ah, a0, wv.x), a1, wv.y);
      }
    }
    #pragma unroll
    for (int jj = 0; jj < 4; ++jj) {
      a2z[jj] += __shfl_xor(a2z[jj], 32);
      a2r[jj] += __shfl_xor(a2r[jj], 32);
    }
    ah += __shfl_xor(ah, 32);
    if (ks == 0) {
      #pragma unroll
      for (int jj = 0; jj < 4; ++jj) {
        my[(6*4+jj)*32 + b] = a2z[jj];
        my[(7*4+jj)*32 + b] = a2r[jj];
      }
      my[1152 + b] = ah;
    }

    __syncthreads();
    // epilogue: tid<64 owns a j-PAIR (j0=jbase+2jp, j0+1) x batch bb
    if (tid < 64) {
      const int jp = tid >> 5, bb = tid & 31;
      const int j0 = jbase + (jp << 1);
      #pragma unroll
      for (int l = 0; l < 3; ++l) {
        float rr[2];
        #pragma unroll
        for (int q = 0; q < 2; ++q) {
          const int jj = (jp << 1) + q;
          float sz = 0.f, sr = 0.f, sg = 0.f;
          #pragma unroll
          for (int ww = 0; ww < 8; ++ww) {
            sz += scratch[ww * 1184 + ((l*3+0)*4 + jj)*32 + bb];
            sr += scratch[ww * 1184 + ((l*3+1)*4 + jj)*32 + bb];
            sg += scratch[ww * 1184 + ((l*3+2)*4 + jj)*32 + bb];
          }
          const int j = j0 + q;
          const float zp = sz + p.bias[l][0][j];
          const float rp = sr + p.bias[l][1][j];
          my_gx[l][q] = sg + p.bias[l][2][j];
          my_z[l][q]  = 1.f / (1.f + expf(-zp));
          const float r = 1.f / (1.f + expf(-rp));
          rr[q] = r * p.hF[l * 32768 + j * 32 + bb];
        }
        unsigned* rq = (l == 0) ? rq0 : (l == 1) ? rq1 : rq2;
        storecu(rq + ((bid << 1) + jp) * 32 + bb, pack2(rr[0], rr[1]));
      }
    }
    if (m >= 3 && bid < 128 && tid < 32) {
      float s = 0.f;
      #pragma unroll
      for (int ww = 0; ww < 8; ++ww) s += scratch[ww * 1184 + 1152 + tid];
      p.out[((size_t)tid << 16) + ((size_t)th << 7) + bid] = s + p.bout[bid];
    }

    ++phase; gridbar(p.bar, phase, bid);

    // ===================== phase 2: fused C ===============================
    float c0[4]={0,0,0,0}, c1[4]={0,0,0,0}, c2[4]={0,0,0,0};
    #pragma unroll 2
    for (int i = 0; i < 16; ++i) {
      const int kp0 = (w << 6) + (i << 2) + (ks << 1);
      const unsigned r00 = loadcu(rq0 + kp0 * 32 + b);
      const unsigned r01 = loadcu(rq0 + (kp0 + 1) * 32 + b);
      const unsigned r10 = loadcu(rq1 + kp0 * 32 + b);
      const unsigned r11 = loadcu(rq1 + (kp0 + 1) * 32 + b);
      const unsigned r20 = loadcu(rq2 + kp0 * 32 + b);
      const unsigned r21 = loadcu(rq2 + (kp0 + 1) * 32 + b);
      #pragma unroll
      for (int jj = 0; jj < 4; ++jj) {
        const int wo = (jj << 9) + kp0;
        uint2 wv;
        wv = *(const uint2*)(lds_u + WH0g + wo); c0[jj] = d2(d2(c0[jj], r00, wv.x), r01, wv.y);
        wv = *(const uint2*)(lds_u + WH1g + wo); c1[jj] = d2(d2(c1[jj], r10, wv.x), r11, wv.y);
        wv = *(const uint2*)(lds_u + WH2g + wo); c2[jj] = d2(d2(c2[jj], r20, wv.x), r21, wv.y);
      }
    }
    #pragma unroll
    for (int jj = 0; jj < 4; ++jj) {
      c0[jj] += __shfl_xor(c0[jj], 32);
      c1[jj] += __shfl_xor(c1[jj], 32);
      c2[jj] += __shfl_xor(c2[jj], 32);
    }
    if (ks == 0) {
      #pragma unroll
      for (int jj = 0; jj < 4; ++jj) {
        my[(0*4+jj)*32 + b] = c0[jj];
        my[(1*4+jj)*32 + b] = c1[jj];
        my[(2*4+jj)*32 + b] = c2[jj];
      }
    }
    __syncthreads();
    if (tid < 64) {
      const int jp = tid >> 5, bb = tid & 31;
      const int j0 = jbase + (jp << 1);
      #pragma unroll
      for (int l = 0; l < 3; ++l) {
        const bool act = (l == 0) ? act0 : (l == 1) ? act1 : act2;
        if (!act) continue;
        const int tl = (l == 0) ? t0 : (l == 1) ? t1 : t2;
        float hb[2];
        #pragma unroll
        for (int q = 0; q < 2; ++q) {
          const int jj = (jp << 1) + q;
          float cv = 0.f;
          #pragma unroll
          for (int ww = 0; ww < 8; ++ww)
            cv += scratch[ww * 1184 + (l*4 + jj)*32 + bb];
          const float g = tanhf(cv + my_gx[l][q]);
          float* hf = p.hF + l * 32768 + (j0 + q) * 32 + bb;
          const float hp = *hf;
          const float hn = my_z[l][q] * hp + (1.f - my_z[l][q]) * g;
          *hf = hn;
          hb[q] = hn;
          if (tl == 511) p.outHid[bb * 3072 + l * 1024 + (j0 + q)] = hn;
        }
        unsigned* hq = (l == 0) ? hP0 : (l == 1) ? hP1 : hP2;
        storecu(hq + ((bid << 1) + jp) * 32 + bb, pack2(hb[0], hb[1]));
      }
    }
    ++phase; gridbar(p.bar, phase, bid);
  } // m

  // final head: t=511
  float ah = 0.f;
  if (bid < 128) {
    #pragma unroll 2
    for (int i = 0; i < 16; ++i) {
      const int kp0 = (w << 6) + (i << 2) + (ks << 1);
      const unsigned a0 = loadcu(hP2 + kp0 * 32 + b);
      const unsigned a1 = loadcu(hP2 + (kp0 + 1) * 32 + b);
      const uint2 wv = *(const uint2*)(lds_u + WOUTO + kp0);
      ah = d2(d2(ah, a0, wv.x), a1, wv.y);
    }
    ah += __shfl_xor(ah, 32);
    if (ks == 0) scratch[w * 1184 + b] = ah;
  }
  __syncthreads();
  if (bid < 128 && tid < 32) {
    float s = 0.f;
    #pragma unroll
    for (int ww = 0; ww < 8; ++ww) s += scratch[ww * 1184 + tid];
    p.out[((size_t)tid << 16) + ((size_t)511 << 7) + bid] = s + p.bout[bid];
  }
}

// Zero hP, rhP, hF, bar (ws poisoned 0xAA before every timed launch).
__global__ void initWs(unsigned* wsd) {
  const int i = blockIdx.x * 1024 + threadIdx.x;
  if (i < 198656) wsd[i] = 0u;
}

extern "C" void kernel_launch(void* const* d_in, const int* in_sizes, int n_in,
                              void* d_out, int out_size, void* d_ws, size_t ws_size,
                              hipStream_t stream)
{
  GruParams P;
  P.x = (const float*)d_in[0];
  P.Wx[0][0] = (const float*)d_in[1];  P.Wh[0][0] = (const float*)d_in[2];
  P.bias[0][0] = (const float*)d_in[3];
  P.Wx[0][1] = (const float*)d_in[4];  P.Wh[0][1] = (const float*)d_in[5];
  P.bias[0][1] = (const float*)d_in[6];
  P.Wx[0][2] = (const float*)d_in[7];  P.Wh[0][2] = (const float*)d_in[8];
  P.bias[0][2] = (const float*)d_in[9];
  for (int l = 1; l < 3; ++l) {
    const size_t off = (size_t)(l - 1) * 1048576;
    const size_t ob  = (size_t)(l - 1) * 1024;
    P.Wx[l][0] = (const float*)d_in[10] + off; P.Wh[l][0] = (const float*)d_in[11] + off;
    P.bias[l][0] = (const float*)d_in[12] + ob;
    P.Wx[l][1] = (const float*)d_in[13] + off; P.Wh[l][1] = (const float*)d_in[14] + off;
    P.bias[l][1] = (const float*)d_in[15] + ob;
    P.Wx[l][2] = (const float*)d_in[16] + off; P.Wh[l][2] = (const float*)d_in[17] + off;
    P.bias[l][2] = (const float*)d_in[18] + ob;
  }
  P.Wout = (const float*)d_in[19];
  P.bout = (const float*)d_in[20];

  char* ws = (char*)d_ws;
  P.hP  = (unsigned*)ws;                 // 3*16384 uints  = 196,608 B
  P.rhP = (unsigned*)(ws + 196608);      // 3*16384 uints  = 196,608 B
  P.hF  = (float*)(ws + 393216);         // 3*32768 f32    = 393,216 B
  P.bar = (unsigned*)(ws + 786432);      // 2048 uints
  P.out = (float*)d_out;
  P.outHid = P.out + 2097152;

  hipFuncSetAttribute(reinterpret_cast<const void*>(gruPersist),
                      hipFuncAttributeMaxDynamicSharedMemorySize, LDSB);

  initWs<<<194, 1024, 0, stream>>>((unsigned*)ws);
  gruPersist<<<256, 512, LDSB, stream>>>(P);
}